// Round 7
// baseline (159.185 us; speedup 1.0000x reference)
//
#include <hip/hip_runtime.h>
#include <hip/hip_bf16.h>

// Shapes (fixed by the problem)
#define NMOVES 4096
#define LW     15
#define DIM    1024
#define VOC    32
#define NROW   480   // VOC * LW distinct (token, position) rows

#define GSPLIT 4            // gram K-split factor
#define KSEG   (DIM/GSPLIT) // 256

typedef __attribute__((ext_vector_type(8))) short  short8;   // 8 bf16 (4 VGPRs)
typedef __attribute__((ext_vector_type(4))) float  floatx4;  // MFMA C/D

__device__ __forceinline__ unsigned short f2b(float f) {
  unsigned int x;
  __builtin_memcpy(&x, &f, 4);
  x = x + 0x7FFFu + ((x >> 16) & 1u);  // round-to-nearest-even
  return (unsigned short)(x >> 16);
}
__device__ __forceinline__ ushort4 cvt4(float4 v) {
  ushort4 o; o.x = f2b(v.x); o.y = f2b(v.y); o.z = f2b(v.z); o.w = f2b(v.w);
  return o;
}

#define LDK 72   // 64 + 8 bf16 pad: 144 B row stride, 16B-aligned

// ---------------------------------------------------------------------------
// K1: fused E-build + QKV projection. C[480,1024] = (letter[t]+pos[l])·W^T + b
// 64x64 tile, 256 thr = 4 waves (2x2), wave does 32x32 via 2x2 fragments of
// mfma_f32_16x16x32_bf16 (fp32 acc). Layouts HW-verified (m89/m91/m120).
// ---------------------------------------------------------------------------
__global__ __launch_bounds__(256) void qkv_fused(
    const float* __restrict__ letter, const float* __restrict__ pos,
    const float* __restrict__ Wq, const float* __restrict__ Wk,
    const float* __restrict__ Wv,
    const float* __restrict__ bq, const float* __restrict__ bk,
    const float* __restrict__ bv,
    float* __restrict__ Qp, float* __restrict__ Kp, float* __restrict__ Vp) {
  __shared__ __attribute__((aligned(16))) unsigned short lA[64 * LDK];
  __shared__ __attribute__((aligned(16))) unsigned short lB[64 * LDK];

  const float* W; const float* bias; float* O;
  if (blockIdx.z == 0)      { W = Wq; bias = bq; O = Qp; }
  else if (blockIdx.z == 1) { W = Wk; bias = bk; O = Kp; }
  else                      { W = Wv; bias = bv; O = Vp; }

  const int bm0 = blockIdx.x * 64;
  const int bn0 = blockIdx.y * 64;

  const int tid  = threadIdx.x;
  const int lane = tid & 63;
  const int wave = tid >> 6;
  const int wr   = wave >> 1;
  const int wc   = wave & 1;
  const int quad = lane >> 4;
  const int l16  = lane & 15;

  const int srow = tid >> 3;          // staging: 32 rows per half-pass
  const int scol = (tid & 7) << 3;    // 8 floats per thread

  const float* arow[2]; const float* prow[2]; bool aval[2];
#pragma unroll
  for (int half = 0; half < 2; ++half) {
    const int gr = bm0 + half * 32 + srow;
    aval[half] = (gr < NROW);
    const int t = gr / LW;
    const int l = gr - t * LW;
    arow[half] = letter + (size_t)t * DIM;
    prow[half] = pos + (size_t)l * DIM;
  }

  floatx4 acc[2][2];
#pragma unroll
  for (int i = 0; i < 2; ++i)
#pragma unroll
    for (int j = 0; j < 2; ++j) acc[i][j] = (floatx4){0.f, 0.f, 0.f, 0.f};

  for (int k0 = 0; k0 < DIM; k0 += 64) {
#pragma unroll
    for (int half = 0; half < 2; ++half) {
      const int r = half * 32 + srow;
      float4 a0 = make_float4(0.f, 0.f, 0.f, 0.f), a1 = a0;
      if (aval[half]) {
        const float* la = arow[half] + k0 + scol;
        const float* lp = prow[half] + k0 + scol;
        float4 x0 = *reinterpret_cast<const float4*>(la);
        float4 x1 = *reinterpret_cast<const float4*>(la + 4);
        float4 p0 = *reinterpret_cast<const float4*>(lp);
        float4 p1 = *reinterpret_cast<const float4*>(lp + 4);
        a0 = make_float4(x0.x + p0.x, x0.y + p0.y, x0.z + p0.z, x0.w + p0.w);
        a1 = make_float4(x1.x + p1.x, x1.y + p1.y, x1.z + p1.z, x1.w + p1.w);
      }
      *reinterpret_cast<ushort4*>(lA + r * LDK + scol)     = cvt4(a0);
      *reinterpret_cast<ushort4*>(lA + r * LDK + scol + 4) = cvt4(a1);

      const int gn = bn0 + r;   // always < 1024
      const float* p = W + (size_t)gn * DIM + k0 + scol;
      float4 b0 = *reinterpret_cast<const float4*>(p);
      float4 b1 = *reinterpret_cast<const float4*>(p + 4);
      *reinterpret_cast<ushort4*>(lB + r * LDK + scol)     = cvt4(b0);
      *reinterpret_cast<ushort4*>(lB + r * LDK + scol + 4) = cvt4(b1);
    }
    __syncthreads();
#pragma unroll
    for (int kk = 0; kk < 64; kk += 32) {
      short8 a0 = *reinterpret_cast<const short8*>(lA + (wr * 32 + l16) * LDK + kk + quad * 8);
      short8 a1 = *reinterpret_cast<const short8*>(lA + (wr * 32 + 16 + l16) * LDK + kk + quad * 8);
      short8 b0 = *reinterpret_cast<const short8*>(lB + (wc * 32 + l16) * LDK + kk + quad * 8);
      short8 b1 = *reinterpret_cast<const short8*>(lB + (wc * 32 + 16 + l16) * LDK + kk + quad * 8);
      acc[0][0] = __builtin_amdgcn_mfma_f32_16x16x32_bf16(a0, b0, acc[0][0], 0, 0, 0);
      acc[0][1] = __builtin_amdgcn_mfma_f32_16x16x32_bf16(a0, b1, acc[0][1], 0, 0, 0);
      acc[1][0] = __builtin_amdgcn_mfma_f32_16x16x32_bf16(a1, b0, acc[1][0], 0, 0, 0);
      acc[1][1] = __builtin_amdgcn_mfma_f32_16x16x32_bf16(a1, b1, acc[1][1], 0, 0, 0);
    }
    __syncthreads();
  }

#pragma unroll
  for (int mi = 0; mi < 2; ++mi) {
#pragma unroll
    for (int ni = 0; ni < 2; ++ni) {
      const int gcol = bn0 + wc * 32 + ni * 16 + l16;
      const float bval = bias[gcol];
#pragma unroll
      for (int i = 0; i < 4; ++i) {
        const int grow = bm0 + wr * 32 + mi * 16 + quad * 4 + i;
        if (grow >= NROW) continue;
        O[(size_t)grow * DIM + gcol] = acc[mi][ni][i] + bval;
      }
    }
  }
}

// ---------------------------------------------------------------------------
// K2: Gram partials. Gpart[p][480,480] = Q'·K'^T over K-segment p (256 wide).
// Grid 8x8x4 = 256 blocks, 4 K-iters each.
// ---------------------------------------------------------------------------
__global__ __launch_bounds__(256) void gram_split(
    const float* __restrict__ Qp, const float* __restrict__ Kp,
    float* __restrict__ Gpart) {
  __shared__ __attribute__((aligned(16))) unsigned short lA[64 * LDK];
  __shared__ __attribute__((aligned(16))) unsigned short lB[64 * LDK];

  const int bm0 = blockIdx.x * 64;
  const int bn0 = blockIdx.y * 64;
  const int kbase = blockIdx.z * KSEG;
  float* Gout = Gpart + (size_t)blockIdx.z * NROW * NROW;

  const int tid  = threadIdx.x;
  const int lane = tid & 63;
  const int wave = tid >> 6;
  const int wr   = wave >> 1;
  const int wc   = wave & 1;
  const int quad = lane >> 4;
  const int l16  = lane & 15;
  const int srow = tid >> 3;
  const int scol = (tid & 7) << 3;

  floatx4 acc[2][2];
#pragma unroll
  for (int i = 0; i < 2; ++i)
#pragma unroll
    for (int j = 0; j < 2; ++j) acc[i][j] = (floatx4){0.f, 0.f, 0.f, 0.f};

  for (int k0 = kbase; k0 < kbase + KSEG; k0 += 64) {
#pragma unroll
    for (int half = 0; half < 2; ++half) {
      const int r = half * 32 + srow;
      float4 a0 = make_float4(0.f, 0.f, 0.f, 0.f), a1 = a0;
      const int gr = bm0 + r;
      if (gr < NROW) {
        const float* p = Qp + (size_t)gr * DIM + k0 + scol;
        a0 = *reinterpret_cast<const float4*>(p);
        a1 = *reinterpret_cast<const float4*>(p + 4);
      }
      *reinterpret_cast<ushort4*>(lA + r * LDK + scol)     = cvt4(a0);
      *reinterpret_cast<ushort4*>(lA + r * LDK + scol + 4) = cvt4(a1);

      float4 b0 = make_float4(0.f, 0.f, 0.f, 0.f), b1 = b0;
      const int gn = bn0 + r;
      if (gn < NROW) {
        const float* p = Kp + (size_t)gn * DIM + k0 + scol;
        b0 = *reinterpret_cast<const float4*>(p);
        b1 = *reinterpret_cast<const float4*>(p + 4);
      }
      *reinterpret_cast<ushort4*>(lB + r * LDK + scol)     = cvt4(b0);
      *reinterpret_cast<ushort4*>(lB + r * LDK + scol + 4) = cvt4(b1);
    }
    __syncthreads();
#pragma unroll
    for (int kk = 0; kk < 64; kk += 32) {
      short8 a0 = *reinterpret_cast<const short8*>(lA + (wr * 32 + l16) * LDK + kk + quad * 8);
      short8 a1 = *reinterpret_cast<const short8*>(lA + (wr * 32 + 16 + l16) * LDK + kk + quad * 8);
      short8 b0 = *reinterpret_cast<const short8*>(lB + (wc * 32 + l16) * LDK + kk + quad * 8);
      short8 b1 = *reinterpret_cast<const short8*>(lB + (wc * 32 + 16 + l16) * LDK + kk + quad * 8);
      acc[0][0] = __builtin_amdgcn_mfma_f32_16x16x32_bf16(a0, b0, acc[0][0], 0, 0, 0);
      acc[0][1] = __builtin_amdgcn_mfma_f32_16x16x32_bf16(a0, b1, acc[0][1], 0, 0, 0);
      acc[1][0] = __builtin_amdgcn_mfma_f32_16x16x32_bf16(a1, b0, acc[1][0], 0, 0, 0);
      acc[1][1] = __builtin_amdgcn_mfma_f32_16x16x32_bf16(a1, b1, acc[1][1], 0, 0, 0);
    }
    __syncthreads();
  }

#pragma unroll
  for (int mi = 0; mi < 2; ++mi) {
#pragma unroll
    for (int ni = 0; ni < 2; ++ni) {
      const int gcol = bn0 + wc * 32 + ni * 16 + l16;
      if (gcol >= NROW) continue;
#pragma unroll
      for (int i = 0; i < 4; ++i) {
        const int grow = bm0 + wr * 32 + mi * 16 + quad * 4 + i;
        if (grow >= NROW) continue;
        Gout[(size_t)grow * NROW + gcol] = acc[mi][ni][i];
      }
    }
  }
}

// ---------------------------------------------------------------------------
// K3: per-move attention, ONE WAVE PER MOVE (4 moves / 256-thread block).
// Per wave: gather S from G partials, softmax rows, column weights, then
// out[m] = sum_j w_j * V'[r_j]. Per-wave LDS slabs; barriers shared by the
// 4 symmetric waves (5 per block vs 5 per move previously).
// ---------------------------------------------------------------------------
__global__ __launch_bounds__(256) void attn_out_k(
    const void* __restrict__ tokens_raw, const float* __restrict__ Gpart,
    const float* __restrict__ Vp, float* __restrict__ out) {
  __shared__ int   ridx[4][16];
  __shared__ float S[4][LW][16];
  __shared__ float w[4][16];
  __shared__ int   is64_s;

  const int tid  = threadIdx.x;
  const int wave = tid >> 6;
  const int lane = tid & 63;
  const int m    = blockIdx.x * 4 + wave;

  const unsigned int* u32 = (const unsigned int*)tokens_raw;
  if (tid < 64) {  // int64 tokens (<32) have all odd 32-bit words zero
    unsigned int v = u32[2 * tid + 1];
    unsigned long long nz = __ballot(v != 0);
    if (tid == 0) is64_s = (nz == 0ULL) ? 1 : 0;
  }
  __syncthreads();

  if (lane < LW) {
    int t;
    if (is64_s) t = (int)((const long long*)tokens_raw)[m * LW + lane];
    else        t = ((const int*)tokens_raw)[m * LW + lane];
    ridx[wave][lane] = t * LW + lane;
  }
  __syncthreads();

  // gather S: 225 entries per wave, 64 lanes -> 4 rounds
  for (int e = lane; e < LW * LW; e += 64) {
    const int l = e / LW;
    const int j = e - l * LW;
    const size_t off = (size_t)ridx[wave][l] * NROW + ridx[wave][j];
    float s = 0.f;
#pragma unroll
    for (int p = 0; p < GSPLIT; ++p) s += Gpart[(size_t)p * NROW * NROW + off];
    S[wave][l][j] = s;
  }
  __syncthreads();

  if (lane < LW) {  // row softmax (lane = row l)
    float mx = -1e30f;
#pragma unroll
    for (int j = 0; j < LW; ++j) mx = fmaxf(mx, S[wave][lane][j]);
    float s = 0.f;
#pragma unroll
    for (int j = 0; j < LW; ++j) {
      float e = __expf(S[wave][lane][j] - mx); S[wave][lane][j] = e; s += e;
    }
    const float inv = 1.0f / s;
#pragma unroll
    for (int j = 0; j < LW; ++j) S[wave][lane][j] *= inv;
  }
  __syncthreads();

  if (lane < LW) {  // column weights (lane = col j), 2x folded in
    float s = 0.f;
#pragma unroll
    for (int l = 0; l < LW; ++l) s += S[wave][l][lane];
    w[wave][lane] = 2.0f * s;
  }
  __syncthreads();

  // accumulate: each lane owns 16 contiguous output cols (4 x float4)
  const int c0 = lane * 16;
  float4 a0 = make_float4(0.f, 0.f, 0.f, 0.f);
  float4 a1 = a0, a2 = a0, a3 = a0;
#pragma unroll
  for (int j = 0; j < LW; ++j) {
    const float wj = w[wave][j];
    const float* vr = Vp + (size_t)ridx[wave][j] * DIM + c0;
    float4 v0 = *reinterpret_cast<const float4*>(vr);
    float4 v1 = *reinterpret_cast<const float4*>(vr + 4);
    float4 v2 = *reinterpret_cast<const float4*>(vr + 8);
    float4 v3 = *reinterpret_cast<const float4*>(vr + 12);
    a0.x += wj * v0.x; a0.y += wj * v0.y; a0.z += wj * v0.z; a0.w += wj * v0.w;
    a1.x += wj * v1.x; a1.y += wj * v1.y; a1.z += wj * v1.z; a1.w += wj * v1.w;
    a2.x += wj * v2.x; a2.y += wj * v2.y; a2.z += wj * v2.z; a2.w += wj * v2.w;
    a3.x += wj * v3.x; a3.y += wj * v3.y; a3.z += wj * v3.z; a3.w += wj * v3.w;
  }
  float* op = out + (size_t)m * DIM + c0;
  *reinterpret_cast<float4*>(op)      = a0;
  *reinterpret_cast<float4*>(op + 4)  = a1;
  *reinterpret_cast<float4*>(op + 8)  = a2;
  *reinterpret_cast<float4*>(op + 12) = a3;
}

// ---------------------------------------------------------------------------
extern "C" void kernel_launch(void* const* d_in, const int* in_sizes, int n_in,
                              void* d_out, int out_size, void* d_ws, size_t ws_size,
                              hipStream_t stream) {
  const void*  tokens = d_in[0];
  const float* letter = (const float*)d_in[1];
  const float* pos    = (const float*)d_in[2];
  const float* Wq     = (const float*)d_in[3];
  const float* bq     = (const float*)d_in[4];
  const float* Wk     = (const float*)d_in[5];
  const float* bk     = (const float*)d_in[6];
  const float* Wv     = (const float*)d_in[7];
  const float* bv     = (const float*)d_in[8];
  float*       outp   = (float*)d_out;   // reference output dtype = float32

  char* ws = (char*)d_ws;
  const size_t SZ = (size_t)NROW * DIM * 4;       // 1.97 MB per [480,1024] fp32
  float* Qp = (float*)(ws);
  float* Kp = (float*)(ws + SZ);
  float* Vp = (float*)(ws + 2 * SZ);
  float* Gp = (float*)(ws + 3 * SZ);              // 4 x 480*480*4 = 3.7 MB

  qkv_fused<<<dim3(8, 16, 3), 256, 0, stream>>>(letter, pos, Wq, Wk, Wv,
                                                bq, bk, bv, Qp, Kp, Vp);
  gram_split<<<dim3(8, 8, GSPLIT), 256, 0, stream>>>(Qp, Kp, Gp);
  attn_out_k<<<NMOVES / 4, 256, 0, stream>>>(tokens, Gp, Vp, outp);
}

// Round 8
// 149.822 us; speedup vs baseline: 1.0625x; 1.0625x over previous
//
#include <hip/hip_runtime.h>
#include <hip/hip_bf16.h>

// Shapes (fixed by the problem)
#define NMOVES 4096
#define LW     15
#define DIM    1024
#define VOC    32
#define NROW   480   // VOC * LW distinct (token, position) rows
#define KPAD   512   // padded K for the output GEMM (480 -> 512)

typedef __attribute__((ext_vector_type(8))) short  short8;   // 8 bf16 (4 VGPRs)
typedef __attribute__((ext_vector_type(4))) float  floatx4;  // MFMA C/D

__device__ __forceinline__ unsigned short f2b(float f) {
  unsigned int x;
  __builtin_memcpy(&x, &f, 4);
  x = x + 0x7FFFu + ((x >> 16) & 1u);  // round-to-nearest-even
  return (unsigned short)(x >> 16);
}
__device__ __forceinline__ ushort4 cvt4(float4 v) {
  ushort4 o; o.x = f2b(v.x); o.y = f2b(v.y); o.z = f2b(v.z); o.w = f2b(v.w);
  return o;
}

#define LDK 72   // 64 + 8 bf16 pad: 144 B row stride, 16B-aligned

// ---------------------------------------------------------------------------
// K1: fused E-build + QKV projection. (letter[t]+pos[l])·W^T + b.
// Emits bf16: Qb[480][1024], Kb[480][1024], and V TRANSPOSED VpT[1024][512]
// (K-contiguous operand for the final A·B^T GEMM; cols 480..511 unwritten).
// 64x64 tile, 4 waves (2x2), mfma_f32_16x16x32_bf16, fp32 accumulate.
// ---------------------------------------------------------------------------
__global__ __launch_bounds__(256) void qkv_fused(
    const float* __restrict__ letter, const float* __restrict__ pos,
    const float* __restrict__ Wq, const float* __restrict__ Wk,
    const float* __restrict__ Wv,
    const float* __restrict__ bq, const float* __restrict__ bk,
    const float* __restrict__ bv,
    unsigned short* __restrict__ Qb, unsigned short* __restrict__ Kb,
    unsigned short* __restrict__ VpT) {
  __shared__ __attribute__((aligned(16))) unsigned short lA[64 * LDK];
  __shared__ __attribute__((aligned(16))) unsigned short lB[64 * LDK];

  const float* W; const float* bias;
  if (blockIdx.z == 0)      { W = Wq; bias = bq; }
  else if (blockIdx.z == 1) { W = Wk; bias = bk; }
  else                      { W = Wv; bias = bv; }

  const int bm0 = blockIdx.x * 64;
  const int bn0 = blockIdx.y * 64;

  const int tid  = threadIdx.x;
  const int lane = tid & 63;
  const int wave = tid >> 6;
  const int wr   = wave >> 1;
  const int wc   = wave & 1;
  const int quad = lane >> 4;
  const int l16  = lane & 15;
  const int srow = tid >> 3;          // staging: 32 rows per half-pass
  const int scol = (tid & 7) << 3;    // 8 floats per thread

  const float* arow[2]; const float* prow[2]; bool aval[2];
#pragma unroll
  for (int half = 0; half < 2; ++half) {
    const int gr = bm0 + half * 32 + srow;
    aval[half] = (gr < NROW);
    const int t = gr / LW;
    const int l = gr - t * LW;
    arow[half] = letter + (size_t)t * DIM;
    prow[half] = pos + (size_t)l * DIM;
  }

  floatx4 acc[2][2];
#pragma unroll
  for (int i = 0; i < 2; ++i)
#pragma unroll
    for (int j = 0; j < 2; ++j) acc[i][j] = (floatx4){0.f, 0.f, 0.f, 0.f};

  for (int k0 = 0; k0 < DIM; k0 += 64) {
#pragma unroll
    for (int half = 0; half < 2; ++half) {
      const int r = half * 32 + srow;
      float4 a0 = make_float4(0.f, 0.f, 0.f, 0.f), a1 = a0;
      if (aval[half]) {
        const float* la = arow[half] + k0 + scol;
        const float* lp = prow[half] + k0 + scol;
        float4 x0 = *reinterpret_cast<const float4*>(la);
        float4 x1 = *reinterpret_cast<const float4*>(la + 4);
        float4 p0 = *reinterpret_cast<const float4*>(lp);
        float4 p1 = *reinterpret_cast<const float4*>(lp + 4);
        a0 = make_float4(x0.x + p0.x, x0.y + p0.y, x0.z + p0.z, x0.w + p0.w);
        a1 = make_float4(x1.x + p1.x, x1.y + p1.y, x1.z + p1.z, x1.w + p1.w);
      }
      *reinterpret_cast<ushort4*>(lA + r * LDK + scol)     = cvt4(a0);
      *reinterpret_cast<ushort4*>(lA + r * LDK + scol + 4) = cvt4(a1);

      const int gn = bn0 + r;   // always < 1024
      const float* p = W + (size_t)gn * DIM + k0 + scol;
      float4 b0 = *reinterpret_cast<const float4*>(p);
      float4 b1 = *reinterpret_cast<const float4*>(p + 4);
      *reinterpret_cast<ushort4*>(lB + r * LDK + scol)     = cvt4(b0);
      *reinterpret_cast<ushort4*>(lB + r * LDK + scol + 4) = cvt4(b1);
    }
    __syncthreads();
#pragma unroll
    for (int kk = 0; kk < 64; kk += 32) {
      short8 a0 = *reinterpret_cast<const short8*>(lA + (wr * 32 + l16) * LDK + kk + quad * 8);
      short8 a1 = *reinterpret_cast<const short8*>(lA + (wr * 32 + 16 + l16) * LDK + kk + quad * 8);
      short8 b0 = *reinterpret_cast<const short8*>(lB + (wc * 32 + l16) * LDK + kk + quad * 8);
      short8 b1 = *reinterpret_cast<const short8*>(lB + (wc * 32 + 16 + l16) * LDK + kk + quad * 8);
      acc[0][0] = __builtin_amdgcn_mfma_f32_16x16x32_bf16(a0, b0, acc[0][0], 0, 0, 0);
      acc[0][1] = __builtin_amdgcn_mfma_f32_16x16x32_bf16(a0, b1, acc[0][1], 0, 0, 0);
      acc[1][0] = __builtin_amdgcn_mfma_f32_16x16x32_bf16(a1, b0, acc[1][0], 0, 0, 0);
      acc[1][1] = __builtin_amdgcn_mfma_f32_16x16x32_bf16(a1, b1, acc[1][1], 0, 0, 0);
    }
    __syncthreads();
  }

  const int z = blockIdx.z;
#pragma unroll
  for (int mi = 0; mi < 2; ++mi) {
#pragma unroll
    for (int ni = 0; ni < 2; ++ni) {
      const int gcol = bn0 + wc * 32 + ni * 16 + l16;
      const float bval = bias[gcol];
#pragma unroll
      for (int i = 0; i < 4; ++i) {
        const int grow = bm0 + wr * 32 + mi * 16 + quad * 4 + i;
        if (grow >= NROW) continue;
        const unsigned short v = f2b(acc[mi][ni][i] + bval);
        if (z == 0)      Qb[(size_t)grow * DIM + gcol] = v;
        else if (z == 1) Kb[(size_t)grow * DIM + gcol] = v;
        else             VpT[(size_t)gcol * KPAD + grow] = v;  // transposed
      }
    }
  }
}

// ---------------------------------------------------------------------------
// K2: G[480,480] = Q·K^T (bf16 in, fp32 out). 64 blocks, 16 K-iters.
// ---------------------------------------------------------------------------
__global__ __launch_bounds__(256) void gram_gemm(
    const unsigned short* __restrict__ Qb, const unsigned short* __restrict__ Kb,
    float* __restrict__ G) {
  __shared__ __attribute__((aligned(16))) unsigned short lA[64 * LDK];
  __shared__ __attribute__((aligned(16))) unsigned short lB[64 * LDK];

  const int bm0 = blockIdx.x * 64;
  const int bn0 = blockIdx.y * 64;

  const int tid  = threadIdx.x;
  const int lane = tid & 63;
  const int wave = tid >> 6;
  const int wr   = wave >> 1;
  const int wc   = wave & 1;
  const int quad = lane >> 4;
  const int l16  = lane & 15;
  const int srow = tid >> 3;
  const int scol = (tid & 7) << 3;

  floatx4 acc[2][2];
#pragma unroll
  for (int i = 0; i < 2; ++i)
#pragma unroll
    for (int j = 0; j < 2; ++j) acc[i][j] = (floatx4){0.f, 0.f, 0.f, 0.f};

  for (int k0 = 0; k0 < DIM; k0 += 64) {
#pragma unroll
    for (int half = 0; half < 2; ++half) {
      const int r = half * 32 + srow;
      uint4 av = make_uint4(0u, 0u, 0u, 0u), bv = av;
      const int gr = bm0 + r;
      if (gr < NROW) av = *reinterpret_cast<const uint4*>(Qb + (size_t)gr * DIM + k0 + scol);
      const int gn = bn0 + r;
      if (gn < NROW) bv = *reinterpret_cast<const uint4*>(Kb + (size_t)gn * DIM + k0 + scol);
      *reinterpret_cast<uint4*>(lA + r * LDK + scol) = av;
      *reinterpret_cast<uint4*>(lB + r * LDK + scol) = bv;
    }
    __syncthreads();
#pragma unroll
    for (int kk = 0; kk < 64; kk += 32) {
      short8 a0 = *reinterpret_cast<const short8*>(lA + (wr * 32 + l16) * LDK + kk + quad * 8);
      short8 a1 = *reinterpret_cast<const short8*>(lA + (wr * 32 + 16 + l16) * LDK + kk + quad * 8);
      short8 b0 = *reinterpret_cast<const short8*>(lB + (wc * 32 + l16) * LDK + kk + quad * 8);
      short8 b1 = *reinterpret_cast<const short8*>(lB + (wc * 32 + 16 + l16) * LDK + kk + quad * 8);
      acc[0][0] = __builtin_amdgcn_mfma_f32_16x16x32_bf16(a0, b0, acc[0][0], 0, 0, 0);
      acc[0][1] = __builtin_amdgcn_mfma_f32_16x16x32_bf16(a0, b1, acc[0][1], 0, 0, 0);
      acc[1][0] = __builtin_amdgcn_mfma_f32_16x16x32_bf16(a1, b0, acc[1][0], 0, 0, 0);
      acc[1][1] = __builtin_amdgcn_mfma_f32_16x16x32_bf16(a1, b1, acc[1][1], 0, 0, 0);
    }
    __syncthreads();
  }

#pragma unroll
  for (int mi = 0; mi < 2; ++mi) {
#pragma unroll
    for (int ni = 0; ni < 2; ++ni) {
      const int gcol = bn0 + wc * 32 + ni * 16 + l16;
      if (gcol >= NROW) continue;
#pragma unroll
      for (int i = 0; i < 4; ++i) {
        const int grow = bm0 + wr * 32 + mi * 16 + quad * 4 + i;
        if (grow >= NROW) continue;
        G[(size_t)grow * NROW + gcol] = acc[mi][ni][i];
      }
    }
  }
}

// ---------------------------------------------------------------------------
// K3: per-move softmax weights -> dense bf16 row of Wmat[4096][512].
// One wave per move (4/block). w_j = 2*sum_l softmax_j(S)[l][j];
// row m of Wmat: w_j at column ridx[j], zero elsewhere (incl. pad 480..511).
// ---------------------------------------------------------------------------
__global__ __launch_bounds__(256) void weights_k(
    const void* __restrict__ tokens_raw, const float* __restrict__ G,
    unsigned short* __restrict__ Wmat) {
  __shared__ int   ridx[4][16];
  __shared__ float S[4][LW][16];
  __shared__ float w[4][16];
  __shared__ int   is64_s;

  const int tid  = threadIdx.x;
  const int wave = tid >> 6;
  const int lane = tid & 63;
  const int m    = blockIdx.x * 4 + wave;

  const unsigned int* u32 = (const unsigned int*)tokens_raw;
  if (tid < 64) {  // int64 tokens (<32) have all odd 32-bit words zero
    unsigned int v = u32[2 * tid + 1];
    unsigned long long nz = __ballot(v != 0);
    if (tid == 0) is64_s = (nz == 0ULL) ? 1 : 0;
  }
  __syncthreads();

  if (lane < LW) {
    int t;
    if (is64_s) t = (int)((const long long*)tokens_raw)[m * LW + lane];
    else        t = ((const int*)tokens_raw)[m * LW + lane];
    ridx[wave][lane] = t * LW + lane;
  }
  __syncthreads();

  for (int e = lane; e < LW * LW; e += 64) {   // gather S (225 entries)
    const int l = e / LW;
    const int j = e - l * LW;
    S[wave][l][j] = G[(size_t)ridx[wave][l] * NROW + ridx[wave][j]];
  }
  __syncthreads();

  if (lane < LW) {  // row softmax (lane = row l)
    float mx = -1e30f;
#pragma unroll
    for (int j = 0; j < LW; ++j) mx = fmaxf(mx, S[wave][lane][j]);
    float s = 0.f;
#pragma unroll
    for (int j = 0; j < LW; ++j) {
      float e = __expf(S[wave][lane][j] - mx); S[wave][lane][j] = e; s += e;
    }
    const float inv = 1.0f / s;
#pragma unroll
    for (int j = 0; j < LW; ++j) S[wave][lane][j] *= inv;
  }
  __syncthreads();

  if (lane < LW) {  // column weights (lane = col j), 2x folded in
    float s = 0.f;
#pragma unroll
    for (int l = 0; l < LW; ++l) s += S[wave][l][lane];
    w[wave][lane] = 2.0f * s;
  }
  __syncthreads();

  // preload (ridx, w) into registers, then emit the dense row
  int   rr[LW]; float wr_[LW];
#pragma unroll
  for (int j = 0; j < LW; ++j) { rr[j] = ridx[wave][j]; wr_[j] = w[wave][j]; }
  unsigned short* row = Wmat + (size_t)m * KPAD;
#pragma unroll
  for (int c = 0; c < KPAD / 64; ++c) {
    const int col = c * 64 + lane;
    float val = 0.f;
#pragma unroll
    for (int j = 0; j < LW; ++j) val = (col == rr[j]) ? wr_[j] : val;
    row[col] = f2b(val);
  }
}

// ---------------------------------------------------------------------------
// K4: out[4096,1024] = Wmat[4096,512] · VpT[1024,512]^T  (bf16 MFMA, fp32 out)
// All dims multiples of 64 -> no guards. Grid (64,16), 8 K-iters.
// ---------------------------------------------------------------------------
__global__ __launch_bounds__(256) void out_gemm(
    const unsigned short* __restrict__ Wmat, const unsigned short* __restrict__ VpT,
    float* __restrict__ out) {
  __shared__ __attribute__((aligned(16))) unsigned short lA[64 * LDK];
  __shared__ __attribute__((aligned(16))) unsigned short lB[64 * LDK];

  const int bm0 = blockIdx.x * 64;
  const int bn0 = blockIdx.y * 64;

  const int tid  = threadIdx.x;
  const int lane = tid & 63;
  const int wave = tid >> 6;
  const int wr   = wave >> 1;
  const int wc   = wave & 1;
  const int quad = lane >> 4;
  const int l16  = lane & 15;
  const int srow = tid >> 3;
  const int scol = (tid & 7) << 3;

  floatx4 acc[2][2];
#pragma unroll
  for (int i = 0; i < 2; ++i)
#pragma unroll
    for (int j = 0; j < 2; ++j) acc[i][j] = (floatx4){0.f, 0.f, 0.f, 0.f};

  for (int k0 = 0; k0 < KPAD; k0 += 64) {
#pragma unroll
    for (int half = 0; half < 2; ++half) {
      const int r = half * 32 + srow;
      uint4 av = *reinterpret_cast<const uint4*>(Wmat + (size_t)(bm0 + r) * KPAD + k0 + scol);
      uint4 bv = *reinterpret_cast<const uint4*>(VpT  + (size_t)(bn0 + r) * KPAD + k0 + scol);
      *reinterpret_cast<uint4*>(lA + r * LDK + scol) = av;
      *reinterpret_cast<uint4*>(lB + r * LDK + scol) = bv;
    }
    __syncthreads();
#pragma unroll
    for (int kk = 0; kk < 64; kk += 32) {
      short8 a0 = *reinterpret_cast<const short8*>(lA + (wr * 32 + l16) * LDK + kk + quad * 8);
      short8 a1 = *reinterpret_cast<const short8*>(lA + (wr * 32 + 16 + l16) * LDK + kk + quad * 8);
      short8 b0 = *reinterpret_cast<const short8*>(lB + (wc * 32 + l16) * LDK + kk + quad * 8);
      short8 b1 = *reinterpret_cast<const short8*>(lB + (wc * 32 + 16 + l16) * LDK + kk + quad * 8);
      acc[0][0] = __builtin_amdgcn_mfma_f32_16x16x32_bf16(a0, b0, acc[0][0], 0, 0, 0);
      acc[0][1] = __builtin_amdgcn_mfma_f32_16x16x32_bf16(a0, b1, acc[0][1], 0, 0, 0);
      acc[1][0] = __builtin_amdgcn_mfma_f32_16x16x32_bf16(a1, b0, acc[1][0], 0, 0, 0);
      acc[1][1] = __builtin_amdgcn_mfma_f32_16x16x32_bf16(a1, b1, acc[1][1], 0, 0, 0);
    }
    __syncthreads();
  }

#pragma unroll
  for (int mi = 0; mi < 2; ++mi) {
#pragma unroll
    for (int ni = 0; ni < 2; ++ni) {
      const int gcol = bn0 + wc * 32 + ni * 16 + l16;
#pragma unroll
      for (int i = 0; i < 4; ++i) {
        const int grow = bm0 + wr * 32 + mi * 16 + quad * 4 + i;
        out[(size_t)grow * DIM + gcol] = acc[mi][ni][i];
      }
    }
  }
}

// ---------------------------------------------------------------------------
extern "C" void kernel_launch(void* const* d_in, const int* in_sizes, int n_in,
                              void* d_out, int out_size, void* d_ws, size_t ws_size,
                              hipStream_t stream) {
  const void*  tokens = d_in[0];
  const float* letter = (const float*)d_in[1];
  const float* pos    = (const float*)d_in[2];
  const float* Wq     = (const float*)d_in[3];
  const float* bq     = (const float*)d_in[4];
  const float* Wk     = (const float*)d_in[5];
  const float* bk     = (const float*)d_in[6];
  const float* Wv     = (const float*)d_in[7];
  const float* bv     = (const float*)d_in[8];
  float*       outp   = (float*)d_out;   // reference output dtype = float32

  char* ws = (char*)d_ws;
  unsigned short* Qb   = (unsigned short*)(ws);                 // 480*1024*2 = 983 KB
  unsigned short* Kb   = (unsigned short*)(ws + (1u << 20));    // 983 KB
  unsigned short* VpT  = (unsigned short*)(ws + (2u << 20));    // 1024*512*2 = 1 MB
  float*          G    = (float*)(ws + (3u << 20));             // 480*480*4 = 922 KB
  unsigned short* Wmat = (unsigned short*)(ws + (4u << 20));    // 4096*512*2 = 4 MB

  qkv_fused<<<dim3(8, 16, 3), 256, 0, stream>>>(letter, pos, Wq, Wk, Wv,
                                                bq, bk, bv, Qb, Kb, VpT);
  gram_gemm<<<dim3(8, 8), 256, 0, stream>>>(Qb, Kb, G);
  weights_k<<<NMOVES / 4, 256, 0, stream>>>(tokens, G, Wmat);
  out_gemm<<<dim3(64, 16), 256, 0, stream>>>(Wmat, VpT, outp);
}